// Round 1
// baseline (110.939 us; speedup 1.0000x reference)
//
#include <hip/hip_runtime.h>
#include <math.h>

#define B_ 512
#define F_ 784
#define R_ 512
#define C_ 16
#define D_ 49
#define HALF_LOG_2PI 0.9189385332046727f

typedef float v2f __attribute__((ext_vector_type(2)));

// Workspace layout (floats):
//   xT : F_*B_        = 401408   (x transposed, so gathers over b are coalesced)
//   PQ : R_*D_*32     = 802816   ([r][d][0:16]=P(c), [r][d][16:32]=Q(c))
//   Kc : R_*C_        = 8192     (per-(r,c) constant term)
// total ~4.63 MB

__global__ __launch_bounds__(256) void k_transpose(const float* __restrict__ x,
                                                   float* __restrict__ xT) {
  int i = blockIdx.x * 256 + threadIdx.x;   // i over B_*F_, coalesced read
  int b = i / F_;
  int f = i - b * F_;
  xT[f * B_ + b] = x[i];
}

__global__ __launch_bounds__(256) void k_coeff(const float* __restrict__ loc,
                                               const float* __restrict__ scale,
                                               float* __restrict__ PQ,
                                               float* __restrict__ Kc) {
  int i = blockIdx.x * 256 + threadIdx.x;   // i = r*C_ + c
  int r = i >> 4;
  int c = i & 15;
  float kacc = 0.f;
  for (int d = 0; d < D_; ++d) {
    float l = loc[i * D_ + d];
    float s = scale[i * D_ + d];
    float P = 0.f, Q = 0.f;
    // Reference: logp is NaN (-> replaced by 0) iff log(s) is NaN/inf-cancelling,
    // i.e. s <= 0 (or non-finite inputs). Independent of x, so decide here.
    bool valid = (s > 0.f) && isfinite(s) && isfinite(l);
    if (valid) {
      float inv  = 1.f / s;
      float inv2 = inv * inv;
      P = -0.5f * inv2;
      Q = l * inv2;
      kacc += -0.5f * l * l * inv2 - logf(s) - HALF_LOG_2PI;
    }
    PQ[(r * D_ + d) * 32 + c]      = P;
    PQ[(r * D_ + d) * 32 + 16 + c] = Q;
  }
  Kc[i] = kacc;
}

__global__ __launch_bounds__(256) void k_main(const float* __restrict__ xT,
                                              const float* __restrict__ PQ,
                                              const float* __restrict__ Kc,
                                              const int* __restrict__ mask,
                                              float* __restrict__ out) {
  const int r = blockIdx.x;
  const int t = threadIdx.x;

  __shared__ float sPQ[D_ * 32];   // 6.27 KB
  __shared__ int   sM[D_];

  for (int i = t; i < D_ * 32; i += 256) sPQ[i] = PQ[r * (D_ * 32) + i];
  if (t < D_) sM[t] = mask[r * D_ + t];

  v2f acc[C_];
#pragma unroll
  for (int c = 0; c < C_; ++c) {
    float k = Kc[r * C_ + c];
    acc[c] = (v2f){k, k};
  }
  __syncthreads();

  const int b0 = 2 * t;   // each thread handles b0, b0+1 (float2-packed)

#pragma unroll 7
  for (int d = 0; d < D_; ++d) {
    const v2f xv  = *(const v2f*)&xT[sM[d] * B_ + b0];  // coalesced 8B/lane
    const v2f xv2 = xv * xv;
    const float* pq = &sPQ[d * 32];   // uniform address -> LDS broadcast
#pragma unroll
    for (int c = 0; c < C_; ++c) {
      float P = pq[c], Q = pq[16 + c];
      acc[c] = __builtin_elementwise_fma((v2f){P, P}, xv2, acc[c]);
      acc[c] = __builtin_elementwise_fma((v2f){Q, Q}, xv, acc[c]);
    }
  }

  // out[b][r][c], c contiguous: two 64B rows per thread
  float4* o0 = (float4*)&out[((size_t)b0 * R_ + r) * C_];
  float4* o1 = (float4*)&out[(((size_t)b0 + 1) * R_ + r) * C_];
#pragma unroll
  for (int q = 0; q < 4; ++q) {
    o0[q] = make_float4(acc[4*q+0].x, acc[4*q+1].x, acc[4*q+2].x, acc[4*q+3].x);
    o1[q] = make_float4(acc[4*q+0].y, acc[4*q+1].y, acc[4*q+2].y, acc[4*q+3].y);
  }
}

extern "C" void kernel_launch(void* const* d_in, const int* in_sizes, int n_in,
                              void* d_out, int out_size, void* d_ws, size_t ws_size,
                              hipStream_t stream) {
  const float* x     = (const float*)d_in[0];
  const int*   mask  = (const int*)  d_in[1];
  const float* loc   = (const float*)d_in[2];
  const float* scale = (const float*)d_in[3];
  float* out = (float*)d_out;

  float* ws = (float*)d_ws;
  float* xT = ws;
  float* PQ = xT + F_ * B_;
  float* Kc = PQ + R_ * D_ * 32;

  hipLaunchKernelGGL(k_transpose, dim3((B_ * F_) / 256), dim3(256), 0, stream, x, xT);
  hipLaunchKernelGGL(k_coeff, dim3((R_ * C_) / 256), dim3(256), 0, stream,
                     loc, scale, PQ, Kc);
  hipLaunchKernelGGL(k_main, dim3(R_), dim3(256), 0, stream, xT, PQ, Kc, mask, out);
}

// Round 2
// 107.531 us; speedup vs baseline: 1.0317x; 1.0317x over previous
//
#include <hip/hip_runtime.h>
#include <math.h>

#define B_ 512
#define F_ 784
#define R_ 512
#define C_ 16
#define D_ 49
#define HALF_LOG_2PI 0.9189385332046727f

typedef float v2f __attribute__((ext_vector_type(2)));

// Workspace layout (floats):
//   xT : F_*B_    = 401408   x transposed -> gathers over b coalesced
//   PQ : R_*D_*32 = 802816   [r][d][0:16]=P(c)=-0.5/s^2, [r][d][16:32]=Q(c)=loc/s^2
//   Kc : R_*C_    = 8192     per-(r,c) constant:  sum_d(-0.5*loc^2/s^2 - log s - c0)
// out[b][r][c] = sum_d P*x_d^2 + Q*x_d + Kc   (pure bilinear form; log/div hoisted)

// ---- 32x32 LDS tile transpose: x[B][F] -> xT[F][B] -------------------------
__global__ __launch_bounds__(256) void k_transpose(const float* __restrict__ x,
                                                   float* __restrict__ xT) {
  __shared__ float tile[32][33];
  const int tx = threadIdx.x & 31;
  const int ty = threadIdx.x >> 5;           // 0..7
  const int f0 = blockIdx.x * 32;            // 25 blocks, last partially OOB
  const int b0 = blockIdx.y * 32;            // 16 blocks
#pragma unroll
  for (int j = 0; j < 4; ++j) {
    int b = b0 + ty + j * 8;
    if (f0 + tx < F_) tile[ty + j * 8][tx] = x[b * F_ + f0 + tx];  // 128B rows
  }
  __syncthreads();
#pragma unroll
  for (int j = 0; j < 4; ++j) {
    int f = f0 + ty + j * 8;
    if (f < F_) xT[(size_t)f * B_ + b0 + tx] = tile[tx][ty + j * 8];  // coalesced
  }
}

// ---- coefficients: block per r, coalesced reads, LDS reduction for Kc ------
__global__ __launch_bounds__(256) void k_coeff(const float* __restrict__ loc,
                                               const float* __restrict__ scale,
                                               float* __restrict__ PQ,
                                               float* __restrict__ Kc) {
  const int r = blockIdx.x;
  const int t = threadIdx.x;
  __shared__ float sTerm[C_ * D_];           // 784 floats
  float* pqr = PQ + (size_t)r * (D_ * 32);

  for (int e = t; e < C_ * D_; e += 256) {   // e = c*D_ + d, coalesced loc/scale
    float l = loc[(size_t)r * C_ * D_ + e];
    float s = scale[(size_t)r * C_ * D_ + e];
    int c = e / D_;
    int d = e - c * D_;
    // Reference maps NaN logp -> 0. logp is NaN iff s<=0 / non-finite inputs,
    // independent of x, so decide validity here and zero the coefficients.
    bool valid = (s > 0.f) && isfinite(s) && isfinite(l);
    float inv2 = valid ? 1.f / (s * s) : 0.f;
    float P = -0.5f * inv2;                  // -0.0f when invalid: harmless
    float Q = l * inv2;
    pqr[d * 32 + c] = P;
    pqr[d * 32 + 16 + c] = Q;
    sTerm[e] = valid ? (-0.5f * l * l * inv2 - __logf(s) - HALF_LOG_2PI) : 0.f;
  }
  __syncthreads();
  if (t < C_) {                              // 16 lanes, stride-49 -> conflict-free
    float k = 0.f;
    for (int d = 0; d < D_; ++d) k += sTerm[t * D_ + d];
    Kc[r * C_ + t] = k;
  }
}

// ---- main: block per r; P/Q/K/mask wave-uniform -> SGPRs; zero LDS ---------
__global__ __launch_bounds__(256) void k_main(const float* __restrict__ xT,
                                              const float* __restrict__ PQ,
                                              const float* __restrict__ Kc,
                                              const int* __restrict__ mask,
                                              float* __restrict__ out) {
  const int r = blockIdx.x;
  const int t = threadIdx.x;
  const int b0 = 2 * t;                      // each thread: b0, b0+1 packed v2f

  const float* __restrict__ pqr = PQ + (size_t)r * (D_ * 32);
  const int* __restrict__ mr = mask + r * D_;
  const float* __restrict__ kr = Kc + r * C_;

  v2f acc[C_];
#pragma unroll
  for (int c = 0; c < C_; ++c) {
    float k = kr[c];                         // uniform -> s_load
    acc[c] = (v2f){k, k};
  }

#pragma unroll 7
  for (int d = 0; d < D_; ++d) {
    const int f = mr[d];                     // uniform -> s_load
    const v2f xv = *(const v2f*)&xT[(size_t)f * B_ + b0];  // 8B/lane coalesced
    const v2f xv2 = xv * xv;
    const float4* pq4 = (const float4*)(pqr + d * 32);     // uniform -> s_load_dwordx4
#pragma unroll
    for (int g = 0; g < 4; ++g) {
      float4 P = pq4[g];
      float4 Q = pq4[4 + g];
      acc[4*g+0] = __builtin_elementwise_fma((v2f){P.x, P.x}, xv2,
                   __builtin_elementwise_fma((v2f){Q.x, Q.x}, xv, acc[4*g+0]));
      acc[4*g+1] = __builtin_elementwise_fma((v2f){P.y, P.y}, xv2,
                   __builtin_elementwise_fma((v2f){Q.y, Q.y}, xv, acc[4*g+1]));
      acc[4*g+2] = __builtin_elementwise_fma((v2f){P.z, P.z}, xv2,
                   __builtin_elementwise_fma((v2f){Q.z, Q.z}, xv, acc[4*g+2]));
      acc[4*g+3] = __builtin_elementwise_fma((v2f){P.w, P.w}, xv2,
                   __builtin_elementwise_fma((v2f){Q.w, Q.w}, xv, acc[4*g+3]));
    }
  }

  // out[b][r][c]: each lane fills its own 64B line with 4x dwordx4
  float4* o0 = (float4*)&out[((size_t)b0 * R_ + r) * C_];
  float4* o1 = (float4*)&out[(((size_t)b0 + 1) * R_ + r) * C_];
#pragma unroll
  for (int q = 0; q < 4; ++q) {
    o0[q] = make_float4(acc[4*q+0].x, acc[4*q+1].x, acc[4*q+2].x, acc[4*q+3].x);
    o1[q] = make_float4(acc[4*q+0].y, acc[4*q+1].y, acc[4*q+2].y, acc[4*q+3].y);
  }
}

extern "C" void kernel_launch(void* const* d_in, const int* in_sizes, int n_in,
                              void* d_out, int out_size, void* d_ws, size_t ws_size,
                              hipStream_t stream) {
  const float* x     = (const float*)d_in[0];
  const int*   mask  = (const int*)  d_in[1];
  const float* loc   = (const float*)d_in[2];
  const float* scale = (const float*)d_in[3];
  float* out = (float*)d_out;

  float* ws = (float*)d_ws;
  float* xT = ws;
  float* PQ = xT + F_ * B_;
  float* Kc = PQ + R_ * D_ * 32;

  hipLaunchKernelGGL(k_transpose, dim3(25, 16), dim3(256), 0, stream, x, xT);
  hipLaunchKernelGGL(k_coeff, dim3(R_), dim3(256), 0, stream, loc, scale, PQ, Kc);
  hipLaunchKernelGGL(k_main, dim3(R_), dim3(256), 0, stream, xT, PQ, Kc, mask, out);
}

// Round 5
// 99.949 us; speedup vs baseline: 1.1100x; 1.0759x over previous
//
#include <hip/hip_runtime.h>
#include <math.h>

#define B_ 512
#define F_ 784
#define R_ 512
#define C_ 16
#define D_ 49
#define PQS (D_ * 32)          // 1568 floats of P/Q per r
#define HALF_LOG_2PI 0.9189385332046727f

typedef float v2f __attribute__((ext_vector_type(2)));

// Workspace (floats):
//   xT : F_*B_    x transposed -> gathers over b coalesced
//   PQ : R_*PQS   [r][d][0:16]=P(c)=-0.5/s^2, [r][d][16:32]=Q(c)=loc/s^2
//   Kc : R_*C_    sum_d(-0.5*loc^2/s^2 - log s - 0.5*log 2pi)
// out[b][r][c] = sum_d P*x_d^2 + Q*x_d + Kc   (log/div hoisted out of hot loop)

// ---- 32x32 LDS tile transpose: x[B][F] -> xT[F][B]  (round-2 proven) -------
__global__ __launch_bounds__(256) void k_transpose(const float* __restrict__ x,
                                                   float* __restrict__ xT) {
  __shared__ float tile[32][33];
  const int tx = threadIdx.x & 31;
  const int ty = threadIdx.x >> 5;           // 0..7
  const int f0 = blockIdx.x * 32;            // 25 blocks, last partially OOB
  const int b0 = blockIdx.y * 32;            // 16 blocks
#pragma unroll
  for (int j = 0; j < 4; ++j) {
    int b = b0 + ty + j * 8;
    if (f0 + tx < F_) tile[ty + j * 8][tx] = x[b * F_ + f0 + tx];  // 128B rows
  }
  __syncthreads();
#pragma unroll
  for (int j = 0; j < 4; ++j) {
    int f = f0 + ty + j * 8;
    if (f < F_) xT[(size_t)f * B_ + b0 + tx] = tile[tx][ty + j * 8];  // coalesced
  }
}

// ---- coefficients: block per r  (round-2 proven) ---------------------------
__global__ __launch_bounds__(256) void k_coeff(const float* __restrict__ loc,
                                               const float* __restrict__ scale,
                                               float* __restrict__ PQ,
                                               float* __restrict__ Kc) {
  const int r = blockIdx.x;
  const int t = threadIdx.x;
  __shared__ float sTerm[C_ * D_];           // 784 floats
  float* pqr = PQ + (size_t)r * PQS;

  for (int e = t; e < C_ * D_; e += 256) {   // e = c*D_ + d, coalesced loc/scale
    float l = loc[(size_t)r * C_ * D_ + e];
    float s = scale[(size_t)r * C_ * D_ + e];
    int c = e / D_;
    int d = e - c * D_;
    // Reference maps NaN logp -> 0. logp is NaN iff s<=0 / non-finite inputs,
    // independent of x, so decide validity here and zero the coefficients.
    bool valid = (s > 0.f) && isfinite(s) && isfinite(l);
    float inv2 = valid ? 1.f / (s * s) : 0.f;
    pqr[d * 32 + c]      = -0.5f * inv2;
    pqr[d * 32 + 16 + c] = l * inv2;
    sTerm[e] = valid ? (-0.5f * l * l * inv2 - __logf(s) - HALF_LOG_2PI) : 0.f;
  }
  __syncthreads();
  if (t < C_) {                              // 16 lanes, stride-49 -> conflict-free
    float k = 0.f;
    for (int d = 0; d < D_; ++d) k += sTerm[t * D_ + d];
    Kc[r * C_ + t] = k;
  }
}

// ---- main: block per r; P/Q/K/mask wave-uniform -> s_loads; LDS-staged store
#define SROW 514                                      // even (b64 align), 2 mod 32
__global__ __launch_bounds__(256) void k_main(const float* __restrict__ xT,
                                              const float* __restrict__ PQ,
                                              const float* __restrict__ Kc,
                                              const int* __restrict__ mask,
                                              float* __restrict__ out) {
  const int r = blockIdx.x;
  const int t = threadIdx.x;
  const int b0 = 2 * t;                               // this thread: b0, b0+1

  const float* __restrict__ pqr = PQ + (size_t)r * PQS;
  const int* __restrict__ mr = mask + r * D_;
  const float* __restrict__ kr = Kc + r * C_;

  __shared__ float sOut[C_ * SROW];                   // [c][b] result staging

  v2f acc[C_];
#pragma unroll
  for (int c = 0; c < C_; ++c) {
    float k = kr[c];                                  // uniform -> s_load
    acc[c] = (v2f){k, k};
  }

#pragma unroll 7
  for (int d = 0; d < D_; ++d) {
    const int f = mr[d];                              // uniform -> s_load
    const v2f xv = *(const v2f*)&xT[(size_t)f * B_ + b0];   // 8B/lane coalesced
    const v2f xv2 = xv * xv;
    const float4* pq4 = (const float4*)(pqr + d * 32);      // uniform -> s_load
#pragma unroll
    for (int g = 0; g < 4; ++g) {
      float4 P = pq4[g];
      float4 Q = pq4[4 + g];
      acc[4*g+0] = __builtin_elementwise_fma((v2f){P.x, P.x}, xv2,
                   __builtin_elementwise_fma((v2f){Q.x, Q.x}, xv, acc[4*g+0]));
      acc[4*g+1] = __builtin_elementwise_fma((v2f){P.y, P.y}, xv2,
                   __builtin_elementwise_fma((v2f){Q.y, Q.y}, xv, acc[4*g+1]));
      acc[4*g+2] = __builtin_elementwise_fma((v2f){P.z, P.z}, xv2,
                   __builtin_elementwise_fma((v2f){Q.z, Q.z}, xv, acc[4*g+2]));
      acc[4*g+3] = __builtin_elementwise_fma((v2f){P.w, P.w}, xv2,
                   __builtin_elementwise_fma((v2f){Q.w, Q.w}, xv, acc[4*g+3]));
    }
  }

  // stage [c][b] in LDS (v2f writes: 2-way bank alias = free), then store with
  // 4 lanes covering each 64B out-line -> 16 lines per store instr instead of 64
#pragma unroll
  for (int c = 0; c < C_; ++c) *(v2f*)&sOut[c * SROW + b0] = acc[c];
  __syncthreads();
#pragma unroll
  for (int k = 0; k < 8; ++k) {
    int j = k * 256 + t;                              // 0..2047
    int b = j >> 2, q = j & 3;                        // lanes 0-3 share line b
    float4 v = make_float4(sOut[(4*q+0) * SROW + b], sOut[(4*q+1) * SROW + b],
                           sOut[(4*q+2) * SROW + b], sOut[(4*q+3) * SROW + b]);
    *(float4*)&out[((size_t)b * R_ + r) * C_ + 4 * q] = v;
  }
}

extern "C" void kernel_launch(void* const* d_in, const int* in_sizes, int n_in,
                              void* d_out, int out_size, void* d_ws, size_t ws_size,
                              hipStream_t stream) {
  const float* x     = (const float*)d_in[0];
  const int*   mask  = (const int*)  d_in[1];
  const float* loc   = (const float*)d_in[2];
  const float* scale = (const float*)d_in[3];
  float* out = (float*)d_out;

  float* ws = (float*)d_ws;
  float* xT = ws;
  float* PQ = xT + F_ * B_;
  float* Kc = PQ + (size_t)R_ * PQS;

  hipLaunchKernelGGL(k_transpose, dim3(25, 16), dim3(256), 0, stream, x, xT);
  hipLaunchKernelGGL(k_coeff, dim3(R_), dim3(256), 0, stream, loc, scale, PQ, Kc);
  hipLaunchKernelGGL(k_main, dim3(R_), dim3(256), 0, stream, xT, PQ, Kc, mask, out);
}

// Round 6
// 97.128 us; speedup vs baseline: 1.1422x; 1.0290x over previous
//
#include <hip/hip_runtime.h>
#include <math.h>

#define B_ 512
#define F_ 784
#define R_ 512
#define C_ 16
#define D_ 49
#define PQS (D_ * 32)          // 1568 floats of P/Q per r
#define HALF_LOG_2PI 0.9189385332046727f

typedef float v2f __attribute__((ext_vector_type(2)));

// Workspace (floats):
//   xT : F_*B_    x transposed -> gathers over b coalesced
//   PQ : R_*PQS   [r][d][0:16]=P(c)=-0.5/s^2, [r][d][16:32]=Q(c)=loc/s^2
//   Kc : R_*C_    sum_d(-0.5*loc^2/s^2 - log s - 0.5*log 2pi)
// out[b][r][c] = sum_d P*x_d^2 + Q*x_d + Kc   (log/div hoisted out of hot loop)

// ---- fused prep: blocks 0..511 = coefficients(r), 512..911 = transpose tiles
__global__ __launch_bounds__(256) void k_prep(const float* __restrict__ x,
                                              const float* __restrict__ loc,
                                              const float* __restrict__ scale,
                                              float* __restrict__ xT,
                                              float* __restrict__ PQ,
                                              float* __restrict__ Kc) {
  const int t = threadIdx.x;
  __shared__ float tile[32][33];       // transpose path (also covers coeff sTerm)
  __shared__ float sTerm[C_ * D_];

  if (blockIdx.x < R_) {
    // ---------------- coefficients for r (round-2-proven body) --------------
    const int r = blockIdx.x;
    float* pqr = PQ + (size_t)r * PQS;
    for (int e = t; e < C_ * D_; e += 256) {         // e = c*49+d, coalesced
      float l = loc[(size_t)r * C_ * D_ + e];
      float s = scale[(size_t)r * C_ * D_ + e];
      int c = e / D_;
      int d = e - c * D_;
      // logp is NaN (ref maps ->0) iff s<=0 / non-finite, independent of x.
      bool valid = (s > 0.f) && isfinite(s) && isfinite(l);
      float inv2 = valid ? 1.f / (s * s) : 0.f;
      pqr[d * 32 + c]      = -0.5f * inv2;
      pqr[d * 32 + 16 + c] = l * inv2;
      sTerm[e] = valid ? (-0.5f * l * l * inv2 - __logf(s) - HALF_LOG_2PI) : 0.f;
    }
    __syncthreads();
    if (t < C_) {                      // 16 lanes, stride-49 -> conflict-free
      float k = 0.f;
      for (int d = 0; d < D_; ++d) k += sTerm[t * D_ + d];
      Kc[r * C_ + t] = k;
    }
  } else {
    // ---------------- 32x32 transpose tile (round-2-proven body) ------------
    const int bi = blockIdx.x - R_;    // 0..399 = 25 x 16
    const int f0 = (bi % 25) * 32;
    const int b0 = (bi / 25) * 32;
    const int tx = t & 31, ty = t >> 5;
#pragma unroll
    for (int j = 0; j < 4; ++j)
      if (f0 + tx < F_) tile[ty + j * 8][tx] = x[(b0 + ty + j * 8) * F_ + f0 + tx];
    __syncthreads();
#pragma unroll
    for (int j = 0; j < 4; ++j) {
      int f = f0 + ty + j * 8;
      if (f < F_) xT[(size_t)f * B_ + b0 + tx] = tile[tx][ty + j * 8];
    }
  }
}

// ---- main: block per r; P/Q/K/mask wave-uniform -> s_loads; LDS-staged store
// (byte-identical to the round-5-validated k_main)
#define SROW 514                                      // even (b64 align), 2 mod 32
__global__ __launch_bounds__(256) void k_main(const float* __restrict__ xT,
                                              const float* __restrict__ PQ,
                                              const float* __restrict__ Kc,
                                              const int* __restrict__ mask,
                                              float* __restrict__ out) {
  const int r = blockIdx.x;
  const int t = threadIdx.x;
  const int b0 = 2 * t;                               // this thread: b0, b0+1

  const float* __restrict__ pqr = PQ + (size_t)r * PQS;
  const int* __restrict__ mr = mask + r * D_;
  const float* __restrict__ kr = Kc + r * C_;

  __shared__ float sOut[C_ * SROW];                   // [c][b] result staging

  v2f acc[C_];
#pragma unroll
  for (int c = 0; c < C_; ++c) {
    float k = kr[c];                                  // uniform -> s_load
    acc[c] = (v2f){k, k};
  }

#pragma unroll 7
  for (int d = 0; d < D_; ++d) {
    const int f = mr[d];                              // uniform -> s_load
    const v2f xv = *(const v2f*)&xT[(size_t)f * B_ + b0];   // 8B/lane coalesced
    const v2f xv2 = xv * xv;
    const float4* pq4 = (const float4*)(pqr + d * 32);      // uniform -> s_load
#pragma unroll
    for (int g = 0; g < 4; ++g) {
      float4 P = pq4[g];
      float4 Q = pq4[4 + g];
      acc[4*g+0] = __builtin_elementwise_fma((v2f){P.x, P.x}, xv2,
                   __builtin_elementwise_fma((v2f){Q.x, Q.x}, xv, acc[4*g+0]));
      acc[4*g+1] = __builtin_elementwise_fma((v2f){P.y, P.y}, xv2,
                   __builtin_elementwise_fma((v2f){Q.y, Q.y}, xv, acc[4*g+1]));
      acc[4*g+2] = __builtin_elementwise_fma((v2f){P.z, P.z}, xv2,
                   __builtin_elementwise_fma((v2f){Q.z, Q.z}, xv, acc[4*g+2]));
      acc[4*g+3] = __builtin_elementwise_fma((v2f){P.w, P.w}, xv2,
                   __builtin_elementwise_fma((v2f){Q.w, Q.w}, xv, acc[4*g+3]));
    }
  }

  // stage [c][b] in LDS (v2f writes: 2-way bank alias = free), then store with
  // 4 lanes covering each 64B out-line -> 16 lines per store instr instead of 64
#pragma unroll
  for (int c = 0; c < C_; ++c) *(v2f*)&sOut[c * SROW + b0] = acc[c];
  __syncthreads();
#pragma unroll
  for (int k = 0; k < 8; ++k) {
    int j = k * 256 + t;                              // 0..2047
    int b = j >> 2, q = j & 3;                        // lanes 0-3 share line b
    float4 v = make_float4(sOut[(4*q+0) * SROW + b], sOut[(4*q+1) * SROW + b],
                           sOut[(4*q+2) * SROW + b], sOut[(4*q+3) * SROW + b]);
    *(float4*)&out[((size_t)b * R_ + r) * C_ + 4 * q] = v;
  }
}

extern "C" void kernel_launch(void* const* d_in, const int* in_sizes, int n_in,
                              void* d_out, int out_size, void* d_ws, size_t ws_size,
                              hipStream_t stream) {
  const float* x     = (const float*)d_in[0];
  const int*   mask  = (const int*)  d_in[1];
  const float* loc   = (const float*)d_in[2];
  const float* scale = (const float*)d_in[3];
  float* out = (float*)d_out;

  float* ws = (float*)d_ws;
  float* xT = ws;
  float* PQ = xT + F_ * B_;
  float* Kc = PQ + (size_t)R_ * PQS;

  hipLaunchKernelGGL(k_prep, dim3(R_ + 400), dim3(256), 0, stream,
                     x, loc, scale, xT, PQ, Kc);
  hipLaunchKernelGGL(k_main, dim3(R_), dim3(256), 0, stream, xT, PQ, Kc, mask, out);
}